// Round 16
// baseline (14360.191 us; speedup 1.0000x reference)
//
#include <hip/hip_runtime.h>
#include <math.h>

// Problem constants (from reference)
#define Bsz   32
#define Lmem  512
#define Tsteps 400
#define EMBD  512
#define PRE   256
#define ENCD  512
#define ARNN  1024
#define DRNN  1024
#define NSYM  256
// MEAN_COEFF = 1.0f, SCALE_COEFF = 10.0f

typedef _Float16 f16x8 __attribute__((ext_vector_type(8)));
typedef float    f32x4 __attribute__((ext_vector_type(4)));
typedef _Float16 half_t;

// ---- 2-barrier (R15) layouts: K = [seg0 | ctx | h] concat ----
#define KA2  (PRE + ENCD + ARNN)    // 1792
#define KA2Q (KA2 / 4)              // 448
#define NMA2 (KA2Q / 32)            // 14
#define KD2  (ARNN + ENCD + DRNN)   // 2560
#define KD2Q (KD2 / 4)              // 640
#define NMD2 (KD2Q / 32)            // 20
#define LDA_A2 1800
#define LDA_D2 2568

// ---- 1-barrier (P-path) layouts: ctx columns removed ----
#define KA1  1280                   // [xpre | ah]
#define KA1Q 320
#define NMA1 10
#define KD1  2048                   // [ah | dh]
#define KD1Q 512
#define NMD1 16
#define LDA_A1 1288
#define LDA_D1 2056
#define WCAP 216

// ---- agent-scope (cross-XCD) sc1 access helpers ---------------------------
__device__ __forceinline__ void st_agent_f16(half_t* p, half_t v) {
    __hip_atomic_store((unsigned short*)p, __builtin_bit_cast(unsigned short, v),
                       __ATOMIC_RELAXED, __HIP_MEMORY_SCOPE_AGENT);
}
__device__ __forceinline__ void st_agent_f32(float* p, float v) {
    __hip_atomic_store(p, v, __ATOMIC_RELAXED, __HIP_MEMORY_SCOPE_AGENT);
}
__device__ __forceinline__ void st_agent_u32(unsigned* p, unsigned v) {
    __hip_atomic_store(p, v, __ATOMIC_RELAXED, __HIP_MEMORY_SCOPE_AGENT);
}
__device__ __forceinline__ void st_agent_u64(unsigned long long* p, unsigned long long v) {
    __hip_atomic_store(p, v, __ATOMIC_RELAXED, __HIP_MEMORY_SCOPE_AGENT);
}
__device__ __forceinline__ float ld_agent_f32(const float* p) {
    return __hip_atomic_load(p, __ATOMIC_RELAXED, __HIP_MEMORY_SCOPE_AGENT);
}
__device__ __forceinline__ unsigned ld_agent_u32(const unsigned* p) {
    return __hip_atomic_load(p, __ATOMIC_RELAXED, __HIP_MEMORY_SCOPE_AGENT);
}
__device__ __forceinline__ unsigned long long ld_agent_u64(const unsigned long long* p) {
    return __hip_atomic_load(p, __ATOMIC_RELAXED, __HIP_MEMORY_SCOPE_AGENT);
}
__device__ __forceinline__ f16x8 ld_agent_f16x8(const half_t* p) {
    union { unsigned long long u[2]; f16x8 v; } c;
    c.u[0] = __hip_atomic_load((const unsigned long long*)p,
                               __ATOMIC_RELAXED, __HIP_MEMORY_SCOPE_AGENT);
    c.u[1] = __hip_atomic_load(((const unsigned long long*)p) + 1,
                               __ATOMIC_RELAXED, __HIP_MEMORY_SCOPE_AGENT);
    return c.v;
}
__device__ __forceinline__ void keep16(f16x8& v) { asm volatile("" : "+v"(v)); }

// ---------------------------------------------------------------------------
// Shared one-time conversion kernels
// ---------------------------------------------------------------------------
// concat layout: [Wih | Whh]
template<int KIH, int KHH>
__global__ __launch_bounds__(256) void conv_lstm_cat(
    const float* __restrict__ Wih, const float* __restrict__ Whh,
    const float* __restrict__ bih, const float* __restrict__ bhh,
    half_t* __restrict__ Wcat, float* __restrict__ bsum)
{
    constexpr int K = KIH + KHH;
    const int j = blockIdx.x;
    const float* srcA = Wih + (size_t)j * KIH;
    const float* srcB = Whh + (size_t)j * KHH;
    half_t* dst = Wcat + (size_t)j * K;
    for (int k = threadIdx.x; k < KIH; k += 256) dst[k]       = (half_t)srcA[k];
    for (int k = threadIdx.x; k < KHH; k += 256) dst[KIH + k] = (half_t)srcB[k];
    if (threadIdx.x == 0) bsum[j] = bih[j] + bhh[j];
}
// skip layout: [Wih[0:L0] | Whh] (ctx cols dropped)
template<int KIH, int KHH, int L0>
__global__ __launch_bounds__(256) void conv_lstm_skip(
    const float* __restrict__ Wih, const float* __restrict__ Whh,
    const float* __restrict__ bih, const float* __restrict__ bhh,
    half_t* __restrict__ Wcat, float* __restrict__ bsum)
{
    constexpr int K = L0 + KHH;
    const int j = blockIdx.x;
    const float* srcA = Wih + (size_t)j * KIH;
    const float* srcB = Whh + (size_t)j * KHH;
    half_t* dst = Wcat + (size_t)j * K;
    for (int k = threadIdx.x; k < L0; k += 256)  dst[k] = (half_t)srcA[k];
    for (int k = threadIdx.x; k < KHH; k += 256) dst[L0 + k] = (half_t)srcB[k];
    if (threadIdx.x == 0) bsum[j] = bih[j] + bhh[j];
}
__global__ __launch_bounds__(256) void conv_slice(
    const float* __restrict__ src, half_t* __restrict__ dst,
    int srcstride, int off, int cols)
{
    const int r = blockIdx.x;
    for (int k = threadIdx.x; k < cols; k += 256)
        dst[(size_t)r * cols + k] = (half_t)src[(size_t)r * srcstride + off + k];
}
__global__ __launch_bounds__(256) void conv_mat(
    const float* __restrict__ src, half_t* __restrict__ dst, int n)
{
    for (int i = blockIdx.x * 256 + threadIdx.x; i < n; i += gridDim.x * 256)
        dst[i] = (half_t)src[i];
}

// ---------------------------------------------------------------------------
// P projection (1-barrier path): P[j][b][l] = sum_d Wsrc[j][Woff+d]*mem[b][l][d]
// Reads fp32 memory directly (no mem16 needed). Block = 32j x 32l for one b.
// ---------------------------------------------------------------------------
__global__ __launch_bounds__(256) void pproj_kernel(
    const float* __restrict__ Wsrc, int Wstride, int Woff,
    const float* __restrict__ mem, half_t* __restrict__ P)
{
    const int bidx = blockIdx.x;
    const int jt  = bidx >> 9;
    const int rem = bidx & 511;
    const int lt  = rem >> 5;
    const int b   = rem & 31;
    const int tid = threadIdx.x;
    const int wave = tid >> 6, lane = tid & 63;
    const int wj = wave >> 1, wl = wave & 1;
    const int m15 = lane & 15, kh = lane >> 4;
    const int j0 = jt * 32 + wj * 16;
    const int l0 = lt * 32 + wl * 16;

    const float* wrow = Wsrc + (size_t)(j0 + m15) * Wstride + Woff + (kh << 3);
    const float* mrow = mem + ((size_t)b * Lmem + (l0 + m15)) * ENCD + (kh << 3);
    f32x4 acc = {0.f, 0.f, 0.f, 0.f};
    for (int k = 0; k < 512; k += 32) {
        float4 w0 = *(const float4*)(wrow + k);
        float4 w1 = *(const float4*)(wrow + k + 4);
        f16x8 av;
        av[0] = (half_t)w0.x; av[1] = (half_t)w0.y; av[2] = (half_t)w0.z; av[3] = (half_t)w0.w;
        av[4] = (half_t)w1.x; av[5] = (half_t)w1.y; av[6] = (half_t)w1.z; av[7] = (half_t)w1.w;
        float4 m0 = *(const float4*)(mrow + k);
        float4 m1 = *(const float4*)(mrow + k + 4);
        f16x8 bv;
        bv[0] = (half_t)m0.x; bv[1] = (half_t)m0.y; bv[2] = (half_t)m0.z; bv[3] = (half_t)m0.w;
        bv[4] = (half_t)m1.x; bv[5] = (half_t)m1.y; bv[6] = (half_t)m1.z; bv[7] = (half_t)m1.w;
        acc = __builtin_amdgcn_mfma_f32_16x16x32_f16(av, bv, acc, 0, 0, 0);
    }
    const int col = lane & 15;
    #pragma unroll
    for (int r = 0; r < 4; ++r) {
        const int row = (kh << 2) + r;
        P[((size_t)(j0 + row) * 32 + b) * 512 + (l0 + col)] = (half_t)acc[r];
    }
}

// ---------------------------------------------------------------------------
// Prenet (shared, one-time): f16 output (T,B,PRE)
// ---------------------------------------------------------------------------
__global__ __launch_bounds__(256) void prenet_kernel(
    const float* __restrict__ din,
    const float* __restrict__ pW1, const float* __restrict__ pb1,
    const float* __restrict__ pW2, const float* __restrict__ pb2,
    half_t* __restrict__ xpre)
{
    __shared__ float xs[8][EMBD];
    __shared__ float h1s[8][PRE];
    const int tid = threadIdx.x;
    const int row0 = blockIdx.x * 8;

    for (int idx = tid; idx < 8 * EMBD; idx += 256) {
        int r = idx >> 9;
        int e = idx & 511;
        int rid = row0 + r;
        int t = rid >> 5;
        int b = rid & 31;
        float v = 0.f;
        if (t > 0) v = din[(size_t)b * EMBD * Tsteps + (size_t)e * Tsteps + (t - 1)];
        xs[r][e] = v;
    }
    __syncthreads();
    {
        float acc[8] = {0.f,0.f,0.f,0.f,0.f,0.f,0.f,0.f};
        const float* wr = pW1 + (size_t)tid * EMBD;
        for (int e = 0; e < EMBD; e += 4) {
            float4 wv = *(const float4*)(wr + e);
            #pragma unroll
            for (int r = 0; r < 8; ++r) {
                float4 xv = *(const float4*)&xs[r][e];
                acc[r] += wv.x * xv.x + wv.y * xv.y + wv.z * xv.z + wv.w * xv.w;
            }
        }
        float bias = pb1[tid];
        #pragma unroll
        for (int r = 0; r < 8; ++r) h1s[r][tid] = fmaxf(acc[r] + bias, 0.f);
    }
    __syncthreads();
    {
        float acc[8] = {0.f,0.f,0.f,0.f,0.f,0.f,0.f,0.f};
        const float* wr = pW2 + (size_t)tid * PRE;
        for (int e = 0; e < PRE; e += 4) {
            float4 wv = *(const float4*)(wr + e);
            #pragma unroll
            for (int r = 0; r < 8; ++r) {
                float4 xv = *(const float4*)&h1s[r][e];
                acc[r] += wv.x * xv.x + wv.y * xv.y + wv.z * xv.z + wv.w * xv.w;
            }
        }
        float bias = pb2[tid];
        #pragma unroll
        for (int r = 0; r < 8; ++r) {
            int rid = row0 + r;
            int t = rid >> 5;
            int b = rid & 31;
            xpre[(size_t)t * Bsz * PRE + (size_t)b * PRE + tid] =
                (half_t)fmaxf(acc[r] + bias, 0.f);
        }
    }
}

// ---------------------------------------------------------------------------
// Flat split-phase RMW-free barrier (proven ~15.8us): arrive + wait.
// ---------------------------------------------------------------------------
__device__ __forceinline__ void g_arrive(unsigned* flags, unsigned ph)
{
    asm volatile("s_waitcnt vmcnt(0)" ::: "memory");
    __syncthreads();
    if (threadIdx.x == 0)
        st_agent_u32(flags + blockIdx.x * 16, ph);
}
__device__ __forceinline__ void g_wait(unsigned* flags, unsigned ph)
{
    if (threadIdx.x < 64) {
        const unsigned* f = flags + threadIdx.x * 64;
        for (;;) {
            unsigned a = ld_agent_u32(f);
            unsigned b = ld_agent_u32(f + 16);
            unsigned c = ld_agent_u32(f + 32);
            unsigned d = ld_agent_u32(f + 48);
            if (min(min(a, b), min(c, d)) >= ph) break;
            __builtin_amdgcn_s_sleep(2);
        }
    }
    __syncthreads();
}

// ===========================================================================
// KERNEL 1: 2-barrier persistent decoder (R15, proven 14.3 ms)
// ===========================================================================
__global__ __launch_bounds__(512, 1) void decoder_2bar(
    const half_t* __restrict__ Wcat_a, const float* __restrict__ bsum_a,
    const half_t* __restrict__ Wcat_d, const float* __restrict__ bsum_d,
    const half_t* __restrict__ Wo, const float* __restrict__ ob,
    const half_t* __restrict__ xpre,
    const float* __restrict__ attWp, const float* __restrict__ attbp,
    const int* __restrict__ mlen, const half_t* __restrict__ mem16,
    half_t* __restrict__ ah0, half_t* __restrict__ ah1,
    half_t* __restrict__ dh0, half_t* __restrict__ dh1,
    half_t* __restrict__ ctx0, half_t* __restrict__ ctx1,
    float* __restrict__ mean0, float* __restrict__ mean1,
    float* __restrict__ logits, float* __restrict__ aligns,
    float* __restrict__ ps,
    unsigned* flags)
{
    const int blk   = blockIdx.x;
    const int tid   = threadIdx.x;
    const int wave  = tid >> 6;
    const int lane  = tid & 63;
    const int btile = wave & 1;
    const int kq    = wave >> 1;
    const int m15   = lane & 15;
    const int kh    = lane >> 4;
    const int u0    = blk << 2;
    const int bb    = (btile << 4) + m15;

    __shared__ __align__(16) half_t wAl[16 * LDA_A2];
    __shared__ __align__(16) half_t wDl[16 * LDA_D2];
    __shared__ float gredA[4][2][16][16];
    __shared__ float gredD[4][2][16][16];
    __shared__ float wsh[Lmem];
    __shared__ float lred[16][33];
    __shared__ float wred8[8][2];
    __shared__ float bc2[2];

    for (int g = tid; g < 16 * (KA2 / 8); g += 512) {
        int r = g / (KA2 / 8);
        int c = (g - r * (KA2 / 8)) * 8;
        int jr = (r >> 2) * 1024 + u0 + (r & 3);
        *(f16x8*)(wAl + r * LDA_A2 + c) = *(const f16x8*)(Wcat_a + (size_t)jr * KA2 + c);
    }
    for (int g = tid; g < 16 * (KD2 / 8); g += 512) {
        int r = g / (KD2 / 8);
        int c = (g - r * (KD2 / 8)) * 8;
        int jr = (r >> 2) * 1024 + u0 + (r & 3);
        *(f16x8*)(wDl + r * LDA_D2 + c) = *(const f16x8*)(Wcat_d + (size_t)jr * KD2 + c);
    }
    float bsA[4] = {0.f,0.f,0.f,0.f}, bsD[4] = {0.f,0.f,0.f,0.f};
    float cA = 0.f, cD = 0.f;
    if (tid < 128) {
        const int ul = tid >> 5;
        #pragma unroll
        for (int gi = 0; gi < 4; ++gi) bsA[gi] = bsum_a[gi * 1024 + u0 + ul];
    } else if (tid < 256) {
        const int ul = (tid - 128) >> 5;
        #pragma unroll
        for (int gi = 0; gi < 4; ++gi) bsD[gi] = bsum_d[gi * 1024 + u0 + ul];
    }
    const half_t* lA = wAl + m15 * LDA_A2 + kq * KA2Q + (kh << 3);
    const half_t* lD = wDl + m15 * LDA_D2 + kq * KD2Q + (kh << 3);
    __syncthreads();

    f16x8 bvA[NMA2], bvD[NMD2];
    {
        const half_t* s0 = xpre;
        #pragma unroll
        for (int i = 0; i < NMA2; ++i) {
            const int kg = kq * KA2Q + i * 32 + (kh << 3);
            if (kg < PRE)             bvA[i] = *(const f16x8*)(s0 + bb * PRE + kg);
            else if (kg < PRE + ENCD) bvA[i] = ld_agent_f16x8(ctx1 + bb * ENCD + (kg - PRE));
            else                      bvA[i] = ld_agent_f16x8(ah1 + bb * ARNN + (kg - PRE - ENCD));
        }
    }

    unsigned ph = 0;

    for (int t = 0; t <= Tsteps; ++t) {
        const int par = t & 1;
        half_t*       ah_cur  = par ? ah1 : ah0;
        half_t*       ctx_cur = par ? ctx1 : ctx0;
        const half_t* ctx_prv = par ? ctx0 : ctx1;
        float*        mn_cur  = par ? mean1 : mean0;
        const float*  mn_prv  = par ? mean0 : mean1;
        half_t*       dh_s    = par ? dh0 : dh1;

        if (t < Tsteps) {
            f32x4 accA = {0.f,0.f,0.f,0.f};
            #pragma unroll
            for (int i = 0; i < NMA2; ++i) {
                f16x8 av = *(const f16x8*)(lA + i * 32);
                accA = __builtin_amdgcn_mfma_f32_16x16x32_f16(av, bvA[i], accA, 0, 0, 0);
            }
            #pragma unroll
            for (int r = 0; r < 4; ++r)
                gredA[kq][btile][(kh << 2) + r][m15] = accA[r];
        }
        if (t > 0) {
            f32x4 accD = {0.f,0.f,0.f,0.f};
            #pragma unroll
            for (int i = 0; i < NMD2; ++i) {
                f16x8 av = *(const f16x8*)(lD + i * 32);
                accD = __builtin_amdgcn_mfma_f32_16x16x32_f16(av, bvD[i], accD, 0, 0, 0);
            }
            #pragma unroll
            for (int r = 0; r < 4; ++r)
                gredD[kq][btile][(kh << 2) + r][m15] = accD[r];
        }
        __syncthreads();
        if (tid < 128) {
            if (t < Tsteps) {
                const int ul = tid >> 5;
                const int bq = tid & 31;
                const int bt = bq >> 4;
                const int nn = bq & 15;
                float g[4];
                #pragma unroll
                for (int gi = 0; gi < 4; ++gi) {
                    const int mr = (gi << 2) + ul;
                    g[gi] = gredA[0][bt][mr][nn] + gredA[1][bt][mr][nn]
                          + gredA[2][bt][mr][nn] + gredA[3][bt][mr][nn] + bsA[gi];
                }
                float si = 1.f / (1.f + expf(-g[0]));
                float sf = 1.f / (1.f + expf(-g[1]));
                float so = 1.f / (1.f + expf(-g[3]));
                cA = sf * cA + si * tanhf(g[2]);
                st_agent_f16(&ah_cur[bq * 1024 + u0 + ul], (half_t)(so * tanhf(cA)));
            }
        } else if (tid < 256) {
            if (t > 0) {
                const int lt = tid - 128;
                const int ul = lt >> 5;
                const int bq = lt & 31;
                const int bt = bq >> 4;
                const int nn = bq & 15;
                float g[4];
                #pragma unroll
                for (int gi = 0; gi < 4; ++gi) {
                    const int mr = (gi << 2) + ul;
                    g[gi] = gredD[0][bt][mr][nn] + gredD[1][bt][mr][nn]
                          + gredD[2][bt][mr][nn] + gredD[3][bt][mr][nn] + bsD[gi];
                }
                float si = 1.f / (1.f + expf(-g[0]));
                float sf = 1.f / (1.f + expf(-g[1]));
                float so = 1.f / (1.f + expf(-g[3]));
                cD = sf * cD + si * tanhf(g[2]);
                st_agent_f16(&dh_s[bq * 1024 + u0 + ul], (half_t)(so * tanhf(cD)));
            }
        }
        ++ph; g_arrive(flags, ph); g_wait(flags, ph);

        if (t < Tsteps) {
            const int abt = blk >> 3;
            const int dt  = blk & 7;
            float p0, p1;
            {
                union { unsigned u; _Float16 h[2]; } a;
                a.u = ld_agent_u32((const unsigned*)(ah_cur + abt * ARNN + 2 * tid));
                float a0 = (float)a.h[0], a1 = (float)a.h[1];
                float2 w0 = *(const float2*)(attWp + 2 * tid);
                float2 w1 = *(const float2*)(attWp + ARNN + 2 * tid);
                p0 = a0 * w0.x + a1 * w0.y;
                p1 = a0 * w1.x + a1 * w1.y;
            }
            #pragma unroll
            for (int off = 32; off > 0; off >>= 1) {
                p0 += __shfl_down(p0, off, 64);
                p1 += __shfl_down(p1, off, 64);
            }
            if (lane == 0) { wred8[wave][0] = p0; wred8[wave][1] = p1; }
            __syncthreads();
            if (tid == 0) {
                float q0 = attbp[0], q1 = attbp[1];
                #pragma unroll
                for (int w = 0; w < 8; ++w) { q0 += wred8[w][0]; q1 += wred8[w][1]; }
                float mn = ld_agent_f32(&mn_prv[abt]) + expf(q0) * 1.0f;
                float sc = expf(q1) * 10.0f;
                if (dt == 0) {
                    st_agent_f32(&mn_cur[abt], mn);
                    st_agent_f32(&ps[(size_t)abt * Tsteps * 2 + (size_t)t * 2 + 0], q0);
                    st_agent_f32(&ps[(size_t)abt * Tsteps * 2 + (size_t)t * 2 + 1], q1);
                }
                bc2[0] = mn; bc2[1] = sc;
            }
            __syncthreads();
            const float mn = bc2[0], sc = bc2[1];
            const float inv_s = 1.f / sc;
            const float coef = 0.3989422804014327f * inv_s;
            const int len = mlen[abt];
            {
                float z = ((float)tid - mn) * inv_s;
                float wv = (tid < len) ? expf(-0.5f * z * z) * coef : 0.f;
                wsh[tid] = wv;
                if (dt == 0)
                    st_agent_f32(&aligns[(size_t)abt * Tsteps * Lmem + (size_t)t * Lmem + tid], wv);
            }
            __syncthreads();
            int lo = (int)fmaxf(0.f, floorf(mn - 9.f * sc));
            int hi = (int)fminf((float)len, ceilf(mn + 9.f * sc) + 1.f);
            const int d8 = (dt << 6) + (wave << 3);
            const half_t* mb = mem16 + (size_t)abt * Lmem * ENCD + d8;
            float acc[8] = {0.f,0.f,0.f,0.f,0.f,0.f,0.f,0.f};
            for (int l = lo + lane; l < hi; l += 64) {
                f16x8 mv = *(const f16x8*)(mb + (size_t)l * ENCD);
                float w = wsh[l];
                #pragma unroll
                for (int j = 0; j < 8; ++j) acc[j] += w * (float)mv[j];
            }
            #pragma unroll
            for (int off = 32; off > 0; off >>= 1) {
                #pragma unroll
                for (int j = 0; j < 8; ++j) acc[j] += __shfl_down(acc[j], off, 64);
            }
            if (lane == 0) {
                #pragma unroll
                for (int j = 0; j < 4; ++j) {
                    union { unsigned u; _Float16 h[2]; } pk;
                    pk.h[0] = (_Float16)acc[2 * j];
                    pk.h[1] = (_Float16)acc[2 * j + 1];
                    __hip_atomic_store((unsigned*)(ctx_cur + abt * ENCD + d8 + 2 * j), pk.u,
                                       __ATOMIC_RELAXED, __HIP_MEMORY_SCOPE_AGENT);
                }
            }
        }
        if (t > 0) {
            const int b_o = tid & 31;
            const int ks  = tid >> 5;
            const half_t* wrow = Wo + (size_t)blk * (DRNN + ENCD) + ks * 96;
            float outacc = 0.f;
            #pragma unroll
            for (int half = 0; half < 2; ++half) {
                f16x8 wv[6], av[6];
                #pragma unroll
                for (int c8 = 0; c8 < 6; ++c8) {
                    const int cc = half * 6 + c8;
                    const int k = ks * 96 + cc * 8;
                    wv[c8] = *(const f16x8*)(wrow + cc * 8);
                    const half_t* ap = (k < DRNN) ? (dh_s + b_o * DRNN + k)
                                                  : (ctx_prv + b_o * ENCD + (k - DRNN));
                    av[c8] = ld_agent_f16x8(ap);
                }
                #pragma unroll
                for (int c8 = 0; c8 < 6; ++c8)
                    #pragma unroll
                    for (int e = 0; e < 8; ++e)
                        outacc += (float)wv[c8][e] * (float)av[c8][e];
            }
            lred[ks][b_o] = outacc;
            __syncthreads();
            if (tid < 32) {
                float s = 0.f;
                #pragma unroll
                for (int q = 0; q < 16; ++q) s += lred[q][tid];
                st_agent_f32(&logits[(size_t)tid * Tsteps * NSYM + (size_t)(t - 1) * NSYM + blk],
                             s + ob[blk]);
            }
        }
        if (t < Tsteps) {
            ++ph; g_arrive(flags, ph);
            if (t + 1 < Tsteps) {
                const half_t* s0n = xpre + (size_t)(t + 1) * Bsz * PRE;
                #pragma unroll
                for (int i = 0; i < NMA2; ++i) {
                    const int kg = kq * KA2Q + i * 32 + (kh << 3);
                    if (kg < PRE)
                        bvA[i] = *(const f16x8*)(s0n + bb * PRE + kg);
                    else if (kg >= PRE + ENCD)
                        bvA[i] = ld_agent_f16x8(ah_cur + bb * ARNN + (kg - PRE - ENCD));
                }
            }
            #pragma unroll
            for (int i = 0; i < NMD2; ++i) {
                const int kg = kq * KD2Q + i * 32 + (kh << 3);
                if (kg < ARNN)
                    bvD[i] = ld_agent_f16x8(ah_cur + bb * ARNN + kg);
                else if (kg >= ARNN + ENCD)
                    bvD[i] = ld_agent_f16x8(dh_s + bb * DRNN + (kg - ARNN - ENCD));
            }
            #pragma unroll
            for (int i = 0; i < NMA2; ++i) keep16(bvA[i]);
            #pragma unroll
            for (int i = 0; i < NMD2; ++i) keep16(bvD[i]);
            g_wait(flags, ph);
            if (t + 1 < Tsteps) {
                #pragma unroll
                for (int i = 0; i < NMA2; ++i) {
                    const int kg = kq * KA2Q + i * 32 + (kh << 3);
                    if (kg >= PRE && kg < PRE + ENCD)
                        bvA[i] = ld_agent_f16x8(ctx_cur + bb * ENCD + (kg - PRE));
                }
            }
            #pragma unroll
            for (int i = 0; i < NMD2; ++i) {
                const int kg = kq * KD2Q + i * 32 + (kh << 3);
                if (kg >= ARNN && kg < ARNN + ENCD)
                    bvD[i] = ld_agent_f16x8(ctx_cur + bb * ENCD + (kg - ARNN));
            }
        }
    }
}

// ===========================================================================
// KERNEL 2: 1-barrier persistent decoder (P-path). ctx eliminated: gate-ctx
// contribution = sum_l w[l]*P[j][b][l]; params redundantly reduced per block.
// ===========================================================================
__global__ __launch_bounds__(512, 2) void decoder_1bar(
    const half_t* __restrict__ Wcat_a, const float* __restrict__ bsum_a,
    const half_t* __restrict__ Wcat_d, const float* __restrict__ bsum_d,
    const half_t* __restrict__ Wo, const float* __restrict__ ob,
    const half_t* __restrict__ xpre,
    const float* __restrict__ attWp, const float* __restrict__ attbp,
    const int* __restrict__ mlen,
    const half_t* __restrict__ P_a, const half_t* __restrict__ P_d,
    const half_t* __restrict__ P_o,
    half_t* __restrict__ ah,
    half_t* __restrict__ dh0, half_t* __restrict__ dh1,
    float* __restrict__ partials,
    float* __restrict__ logits, float* __restrict__ aligns,
    float* __restrict__ ps,
    unsigned* flags)
{
    const int blk   = blockIdx.x;
    const int tid   = threadIdx.x;
    const int wave  = tid >> 6;
    const int lane  = tid & 63;
    const int btile = wave & 1;
    const int kq    = wave >> 1;
    const int m15   = lane & 15;
    const int kh    = lane >> 4;
    const int u0    = blk << 2;
    const int bb    = (btile << 4) + m15;

    __shared__ __align__(16) half_t wAl[16 * LDA_A1];
    __shared__ __align__(16) half_t wDl[16 * LDA_D1];
    __shared__ float gredA[4][2][16][16];
    __shared__ float gredD[4][2][16][16];
    __shared__ float wshc[32][WCAP + 8];
    __shared__ float ctxA[16][32];
    __shared__ float ctxD[16][32];
    __shared__ float ctxO[32];
    __shared__ float lred[16][33];
    __shared__ float part[4][32][2];
    __shared__ float praw[32][2];
    __shared__ float bcc[32][4];
    __shared__ float bcp[32][4];
    __shared__ int   lacur[32], hicur[32];
    __shared__ int   lapv[32], hipv[32];
    __shared__ float mean32[32];
    __shared__ half_t hstA[4][32], hstD[4][32];

    for (int g = tid; g < 16 * (KA1 / 8); g += 512) {
        int r = g / (KA1 / 8);
        int c = (g - r * (KA1 / 8)) * 8;
        int jr = (r >> 2) * 1024 + u0 + (r & 3);
        *(f16x8*)(wAl + r * LDA_A1 + c) = *(const f16x8*)(Wcat_a + (size_t)jr * KA1 + c);
    }
    for (int g = tid; g < 16 * (KD1 / 8); g += 512) {
        int r = g / (KD1 / 8);
        int c = (g - r * (KD1 / 8)) * 8;
        int jr = (r >> 2) * 1024 + u0 + (r & 3);
        *(f16x8*)(wDl + r * LDA_D1 + c) = *(const f16x8*)(Wcat_d + (size_t)jr * KD1 + c);
    }
    float bsA[4] = {0.f,0.f,0.f,0.f}, bsD[4] = {0.f,0.f,0.f,0.f};
    float wp0 = 0.f, wp1 = 0.f;
    float cA = 0.f, cD = 0.f;
    if (tid < 128) {
        const int ul = tid >> 5;
        #pragma unroll
        for (int gi = 0; gi < 4; ++gi) bsA[gi] = bsum_a[gi * 1024 + u0 + ul];
        wp0 = attWp[u0 + ul];
        wp1 = attWp[ARNN + u0 + ul];
    } else if (tid < 256) {
        const int ul = (tid - 128) >> 5;
        #pragma unroll
        for (int gi = 0; gi < 4; ++gi) bsD[gi] = bsum_d[gi * 1024 + u0 + ul];
    }
    if (tid < 32) mean32[tid] = 0.f;
    const half_t* lA = wAl + m15 * LDA_A1 + kq * KA1Q + (kh << 3);
    const half_t* lD = wDl + m15 * LDA_D1 + kq * KD1Q + (kh << 3);
    __syncthreads();

    f16x8 bvA[NMA1], bvD[NMD1];
    #pragma unroll
    for (int i = 0; i < NMA1; ++i) {
        const int kg = kq * KA1Q + i * 32 + (kh << 3);
        if (kg < PRE) bvA[i] = *(const f16x8*)(xpre + bb * PRE + kg);
        else          bvA[i] = ld_agent_f16x8(ah + bb * ARNN + (kg - PRE));
    }

    unsigned ph = 0;

    for (int tau = 0; tau <= Tsteps + 1; ++tau) {
        const int par = tau & 1;
        half_t*       dhW = par ? dh1 : dh0;
        const half_t* dhR = par ? dh0 : dh1;

        // ---- STAGE 0: params for step tau-1 ----
        if (tau >= 1) {
            if (tid < 32) {
                bcp[tid][0] = bcc[tid][0]; bcp[tid][1] = bcc[tid][1]; bcp[tid][2] = bcc[tid][2];
                lapv[tid] = lacur[tid]; hipv[tid] = hicur[tid];
            }
            __syncthreads();
        }
        if (tau >= 1 && tau <= Tsteps) {
            {
                const int b = tid >> 4, c = tid & 15;
                const unsigned long long* pb =
                    (const unsigned long long*)(partials + ((size_t)b * 256 + c * 16) * 2);
                float s0 = 0.f, s1 = 0.f;
                #pragma unroll
                for (int q = 0; q < 16; ++q) {
                    union { unsigned long long u; float2 f; } v;
                    v.u = ld_agent_u64(pb + q);
                    s0 += v.f.x; s1 += v.f.y;
                }
                s0 += __shfl_down(s0, 8, 16); s1 += __shfl_down(s1, 8, 16);
                s0 += __shfl_down(s0, 4, 16); s1 += __shfl_down(s1, 4, 16);
                s0 += __shfl_down(s0, 2, 16); s1 += __shfl_down(s1, 2, 16);
                s0 += __shfl_down(s0, 1, 16); s1 += __shfl_down(s1, 1, 16);
                if (c == 0) { praw[b][0] = s0; praw[b][1] = s1; }
            }
            __syncthreads();
            if (tid < 32) {
                float q0 = praw[tid][0] + attbp[0];
                float q1 = praw[tid][1] + attbp[1];
                float mn = mean32[tid] + expf(q0);
                mean32[tid] = mn;
                float sc = 10.f * expf(q1);
                float inv_s = 1.f / sc;
                bcc[tid][0] = mn; bcc[tid][1] = inv_s;
                bcc[tid][2] = 0.3989422804014327f * inv_s;
                int len = mlen[tid];
                int lo = (int)fmaxf(0.f, floorf(mn - 6.f * sc));
                int hi = (int)fminf((float)len, ceilf(mn + 6.f * sc) + 1.f);
                if (hi - lo > WCAP) {
                    int mid = (lo + hi) >> 1;
                    lo = mid - WCAP / 2; hi = lo + WCAP;
                    if (lo < 0) { lo = 0; hi = WCAP; }
                    if (hi > len) { hi = len; lo = hi - WCAP; if (lo < 0) lo = 0; }
                }
                if (hi < lo) hi = lo;
                lacur[tid] = lo & ~7;
                hicur[tid] = hi;
                if (blk == tid) {
                    st_agent_f32(&ps[((size_t)tid * Tsteps + (tau - 1)) * 2 + 0], q0);
                    st_agent_f32(&ps[((size_t)tid * Tsteps + (tau - 1)) * 2 + 1], q1);
                }
            }
            __syncthreads();
            {
                const int b = tid >> 4, c = tid & 15;
                const int la = lacur[b], hi = hicur[b];
                const float mn = bcc[b][0], inv_s = bcc[b][1], coef = bcc[b][2];
                for (int i = c; i < WCAP + 8; i += 16) {
                    int l = la + i;
                    float w = 0.f;
                    if (l < hi) {
                        float z = ((float)l - mn) * inv_s;
                        w = coef * expf(-0.5f * z * z);
                    }
                    wshc[b][i] = w;
                }
            }
            if (blk < 32) {
                const int len = mlen[blk];
                const float mn = bcc[blk][0], inv_s = bcc[blk][1], coef = bcc[blk][2];
                float z = ((float)tid - mn) * inv_s;
                float w = (tid < len) ? coef * expf(-0.5f * z * z) : 0.f;
                st_agent_f32(&aligns[((size_t)blk * Tsteps + (tau - 1)) * Lmem + tid], w);
            }
            __syncthreads();
        }

        // ---- STAGE 1: main compute ----
        if (tau < Tsteps) {
            f32x4 accA = {0.f,0.f,0.f,0.f};
            #pragma unroll
            for (int i = 0; i < NMA1; ++i) {
                f16x8 av = *(const f16x8*)(lA + i * 32);
                accA = __builtin_amdgcn_mfma_f32_16x16x32_f16(av, bvA[i], accA, 0, 0, 0);
            }
            #pragma unroll
            for (int r = 0; r < 4; ++r)
                gredA[kq][btile][(kh << 2) + r][m15] = accA[r];
        }
        if (tau >= 1 && tau <= Tsteps) {
            f32x4 accD = {0.f,0.f,0.f,0.f};
            #pragma unroll
            for (int i = 0; i < NMD1; ++i) {
                f16x8 av = *(const f16x8*)(lD + i * 32);
                accD = __builtin_amdgcn_mfma_f32_16x16x32_f16(av, bvD[i], accD, 0, 0, 0);
            }
            #pragma unroll
            for (int r = 0; r < 4; ++r)
                gredD[kq][btile][(kh << 2) + r][m15] = accD[r];
        }
        if (tau >= 2) {
            const int b_o = tid & 31;
            const int ks  = tid >> 5;
            const half_t* wrow = Wo + (size_t)blk * DRNN + ks * 64;
            const half_t* ap   = dhR + (size_t)b_o * DRNN + ks * 64;
            float outacc = 0.f;
            #pragma unroll
            for (int c8 = 0; c8 < 8; ++c8) {
                f16x8 wv = *(const f16x8*)(wrow + c8 * 8);
                f16x8 av = ld_agent_f16x8(ap + c8 * 8);
                #pragma unroll
                for (int e = 0; e < 8; ++e)
                    outacc += (float)wv[e] * (float)av[e];
            }
            lred[ks][b_o] = outacc;
        }
        if (tau >= 1 && tau <= Tsteps) {
            const int jl = tid >> 5, b = tid & 31;
            const int jg = (jl >> 2) * 1024 + u0 + (jl & 3);
            const int la = lacur[b], hi = hicur[b];
            const int nv = (hi - la + 7) >> 3;
            const half_t* pa = P_a + ((size_t)jg * 32 + b) * 512 + la;
            const half_t* pd = P_d + ((size_t)jg * 32 + b) * 512 + la;
            float sA = 0.f, sD = 0.f;
            for (int v = 0; v < nv; ++v) {
                f16x8 pav = *(const f16x8*)(pa + v * 8);
                f16x8 pdv = *(const f16x8*)(pd + v * 8);
                #pragma unroll
                for (int e = 0; e < 8; ++e) {
                    float w = wshc[b][v * 8 + e];
                    sA += w * (float)pav[e];
                    sD += w * (float)pdv[e];
                }
            }
            ctxA[jl][b] = sA;
            ctxD[jl][b] = sD;
        }
        if (tau >= 2 && tid >= 448 && tid < 480) {
            const int b = tid - 448;
            const int la = lapv[b], hi = hipv[b];
            const float mn = bcp[b][0], inv_s = bcp[b][1], coef = bcp[b][2];
            const half_t* po = P_o + ((size_t)blk * 32 + b) * 512 + la;
            float s = 0.f;
            const int nv = (hi - la + 7) >> 3;
            for (int v = 0; v < nv; ++v) {
                f16x8 pov = *(const f16x8*)(po + v * 8);
                #pragma unroll
                for (int e = 0; e < 8; ++e) {
                    int l = la + v * 8 + e;
                    if (l < hi) {
                        float z = ((float)l - mn) * inv_s;
                        s += coef * expf(-0.5f * z * z) * (float)pov[e];
                    }
                }
            }
            ctxO[b] = s;
        }
        __syncthreads();

        // ---- STAGE 2: epilogues ----
        if (tid < 128) {
            if (tau < Tsteps) {
                const int ul = tid >> 5;
                const int bq = tid & 31;
                const int bt = bq >> 4;
                const int nn = bq & 15;
                float g[4];
                #pragma unroll
                for (int gi = 0; gi < 4; ++gi) {
                    const int mr = (gi << 2) + ul;
                    g[gi] = gredA[0][bt][mr][nn] + gredA[1][bt][mr][nn]
                          + gredA[2][bt][mr][nn] + gredA[3][bt][mr][nn] + bsA[gi]
                          + ((tau >= 1) ? ctxA[mr][bq] : 0.f);
                }
                float si = 1.f / (1.f + expf(-g[0]));
                float sf = 1.f / (1.f + expf(-g[1]));
                float so = 1.f / (1.f + expf(-g[3]));
                cA = sf * cA + si * tanhf(g[2]);
                float hval = so * tanhf(cA);
                hstA[ul][bq] = (half_t)hval;
                part[ul][bq][0] = hval * wp0;
                part[ul][bq][1] = hval * wp1;
            }
        } else if (tid < 256) {
            if (tau >= 1 && tau <= Tsteps) {
                const int lt = tid - 128;
                const int ul = lt >> 5;
                const int bq = lt & 31;
                const int bt = bq >> 4;
                const int nn = bq & 15;
                float g[4];
                #pragma unroll
                for (int gi = 0; gi < 4; ++gi) {
                    const int mr = (gi << 2) + ul;
                    g[gi] = gredD[0][bt][mr][nn] + gredD[1][bt][mr][nn]
                          + gredD[2][bt][mr][nn] + gredD[3][bt][mr][nn] + bsD[gi]
                          + ctxD[mr][bq];
                }
                float si = 1.f / (1.f + expf(-g[0]));
                float sf = 1.f / (1.f + expf(-g[1]));
                float so = 1.f / (1.f + expf(-g[3]));
                cD = sf * cD + si * tanhf(g[2]);
                hstD[ul][bq] = (half_t)(so * tanhf(cD));
            }
        } else if (tid < 288) {
            if (tau >= 2) {
                const int b = tid - 256;
                float s = 0.f;
                #pragma unroll
                for (int q = 0; q < 16; ++q) s += lred[q][b];
                st_agent_f32(&logits[(size_t)b * Tsteps * NSYM + (size_t)(tau - 2) * NSYM + blk],
                             s + ctxO[b] + ob[blk]);
            }
        }
        __syncthreads();
        if (tau < Tsteps && tid < 32) {
            union { unsigned long long u; half_t h[4]; } pk;
            #pragma unroll
            for (int q = 0; q < 4; ++q) pk.h[q] = hstA[q][tid];
            st_agent_u64((unsigned long long*)(ah + (size_t)tid * ARNN + u0), pk.u);
            float p0 = part[0][tid][0] + part[1][tid][0] + part[2][tid][0] + part[3][tid][0];
            float p1 = part[0][tid][1] + part[1][tid][1] + part[2][tid][1] + part[3][tid][1];
            union { float2 f; unsigned long long u; } pp;
            pp.f.x = p0; pp.f.y = p1;
            st_agent_u64((unsigned long long*)(partials + ((size_t)tid * 256 + blk) * 2), pp.u);
        }
        if (tau >= 1 && tau <= Tsteps && tid >= 64 && tid < 96) {
            const int b = tid - 64;
            union { unsigned long long u; half_t h[4]; } pk;
            #pragma unroll
            for (int q = 0; q < 4; ++q) pk.h[q] = hstD[q][b];
            st_agent_u64((unsigned long long*)(dhW + (size_t)b * DRNN + u0), pk.u);
        }

        // ---- ONE barrier + next-phase fragment loads ----
        if (tau <= Tsteps) {
            ++ph; g_arrive(flags, ph);
            if (tau + 1 < Tsteps) {
                const half_t* s0n = xpre + (size_t)(tau + 1) * Bsz * PRE;
                #pragma unroll
                for (int i = 0; i < NMA1; ++i) {
                    const int kg = kq * KA1Q + i * 32 + (kh << 3);
                    if (kg < PRE) { bvA[i] = *(const f16x8*)(s0n + bb * PRE + kg); keep16(bvA[i]); }
                }
            }
            g_wait(flags, ph);
            if (tau + 1 < Tsteps) {
                #pragma unroll
                for (int i = 0; i < NMA1; ++i) {
                    const int kg = kq * KA1Q + i * 32 + (kh << 3);
                    if (kg >= PRE) { bvA[i] = ld_agent_f16x8(ah + bb * ARNN + (kg - PRE)); keep16(bvA[i]); }
                }
            }
            if (tau < Tsteps) {
                #pragma unroll
                for (int i = 0; i < NMD1; ++i) {
                    const int kg = kq * KD1Q + i * 32 + (kh << 3);
                    bvD[i] = (kg < ARNN) ? ld_agent_f16x8(ah + bb * ARNN + kg)
                                         : ld_agent_f16x8(dhW + bb * DRNN + (kg - ARNN));
                    keep16(bvD[i]);
                }
            }
        }
    }
}

// ---------------------------------------------------------------------------
extern "C" void kernel_launch(void* const* d_in, const int* in_sizes, int n_in,
                              void* d_out, int out_size, void* d_ws, size_t ws_size,
                              hipStream_t stream)
{
    (void)in_sizes; (void)n_in; (void)out_size;
    const float* memory = (const float*)d_in[0];
    const float* din    = (const float*)d_in[1];
    const int*   mlen   = (const int*)d_in[2];
    const float* pW1    = (const float*)d_in[3];
    const float* pb1    = (const float*)d_in[4];
    const float* pW2    = (const float*)d_in[5];
    const float* pb2    = (const float*)d_in[6];
    const float* aWih   = (const float*)d_in[7];
    const float* aWhh   = (const float*)d_in[8];
    const float* abih   = (const float*)d_in[9];
    const float* abhh   = (const float*)d_in[10];
    const float* attWp  = (const float*)d_in[11];
    const float* attbp  = (const float*)d_in[12];
    const float* dWih   = (const float*)d_in[13];
    const float* dWhh   = (const float*)d_in[14];
    const float* dbih   = (const float*)d_in[15];
    const float* dbhh   = (const float*)d_in[16];
    const float* oW     = (const float*)d_in[17];
    const float* ob     = (const float*)d_in[18];

    float* logits = (float*)d_out;
    float* aligns = logits + (size_t)Bsz * Tsteps * NSYM;
    float* ps     = aligns + (size_t)Bsz * Tsteps * Lmem;

    char* base = (char*)d_ws;
    auto alloc = [&](size_t bytes) -> char* {
        char* p = base; base += (bytes + 255) & ~(size_t)255; return p;
    };

    if (ws_size >= ((size_t)320 << 20)) {
        // ================= 1-barrier P-path =================
        half_t* Wcat_a = (half_t*)alloc((size_t)4096 * KA1 * 2);
        half_t* Wcat_d = (half_t*)alloc((size_t)4096 * KD1 * 2);
        half_t* Wo     = (half_t*)alloc((size_t)NSYM * DRNN * 2);
        float*  bsum_a = (float*)alloc(4096 * 4);
        float*  bsum_d = (float*)alloc(4096 * 4);
        half_t* xpre   = (half_t*)alloc((size_t)Tsteps * Bsz * PRE * 2);
        half_t* P_a    = (half_t*)alloc((size_t)4096 * 32 * 512 * 2);
        half_t* P_d    = (half_t*)alloc((size_t)4096 * 32 * 512 * 2);
        half_t* P_o    = (half_t*)alloc((size_t)256 * 32 * 512 * 2);
        half_t* ah     = (half_t*)alloc(Bsz * ARNN * 2);
        half_t* dh0    = (half_t*)alloc(Bsz * DRNN * 2);
        half_t* dh1    = (half_t*)alloc(Bsz * DRNN * 2);
        float*  partials = (float*)alloc((size_t)Bsz * 256 * 2 * 4);
        unsigned* flags  = (unsigned*)alloc(256 * 16 * 4);

        (void)hipMemsetAsync(ah,   0, Bsz * ARNN * 2, stream);
        (void)hipMemsetAsync(dh0,  0, Bsz * DRNN * 2, stream);
        (void)hipMemsetAsync(dh1,  0, Bsz * DRNN * 2, stream);
        (void)hipMemsetAsync(flags, 0, 256 * 16 * 4, stream);

        conv_lstm_skip<768, 1024, 256><<<4096, 256, 0, stream>>>(
            aWih, aWhh, abih, abhh, Wcat_a, bsum_a);
        conv_lstm_skip<1536, 1024, 1024><<<4096, 256, 0, stream>>>(
            dWih, dWhh, dbih, dbhh, Wcat_d, bsum_d);
        conv_slice<<<256, 256, 0, stream>>>(oW, Wo, 1536, 0, 1024);
        prenet_kernel<<<Tsteps * Bsz / 8, 256, 0, stream>>>(din, pW1, pb1, pW2, pb2, xpre);
        pproj_kernel<<<(4096 / 32) * 512, 256, 0, stream>>>(aWih, 768, 256, memory, P_a);
        pproj_kernel<<<(4096 / 32) * 512, 256, 0, stream>>>(dWih, 1536, 1024, memory, P_d);
        pproj_kernel<<<(256 / 32) * 512, 256, 0, stream>>>(oW, 1536, 1024, memory, P_o);

        decoder_1bar<<<256, 512, 0, stream>>>(
            Wcat_a, bsum_a, Wcat_d, bsum_d, Wo, ob, xpre,
            attWp, attbp, mlen, P_a, P_d, P_o,
            ah, dh0, dh1, partials,
            logits, aligns, ps, flags);
    } else {
        // ================= 2-barrier R15 path (proven) =================
        half_t* Wcat_a = (half_t*)alloc((size_t)4096 * KA2 * 2);
        half_t* Wcat_d = (half_t*)alloc((size_t)4096 * KD2 * 2);
        half_t* Wo     = (half_t*)alloc((size_t)NSYM * (DRNN + ENCD) * 2);
        float*  bsum_a = (float*)alloc(4096 * 4);
        float*  bsum_d = (float*)alloc(4096 * 4);
        half_t* xpre   = (half_t*)alloc((size_t)Tsteps * Bsz * PRE * 2);
        half_t* mem16  = (half_t*)alloc((size_t)Bsz * Lmem * ENCD * 2);
        half_t* ah0    = (half_t*)alloc(Bsz * ARNN * 2);
        half_t* ah1    = (half_t*)alloc(Bsz * ARNN * 2);
        half_t* dh0    = (half_t*)alloc(Bsz * DRNN * 2);
        half_t* dh1    = (half_t*)alloc(Bsz * DRNN * 2);
        half_t* ctx0   = (half_t*)alloc(Bsz * ENCD * 2);
        half_t* ctx1   = (half_t*)alloc(Bsz * ENCD * 2);
        float*  mean0  = (float*)alloc(Bsz * 4);
        float*  mean1  = (float*)alloc(Bsz * 4);
        unsigned* flags = (unsigned*)alloc(256 * 16 * 4);

        (void)hipMemsetAsync(ah1,   0, Bsz * ARNN * 2, stream);
        (void)hipMemsetAsync(dh1,   0, Bsz * DRNN * 2, stream);
        (void)hipMemsetAsync(ctx1,  0, Bsz * ENCD * 2, stream);
        (void)hipMemsetAsync(mean0, 0, Bsz * 4, stream);
        (void)hipMemsetAsync(mean1, 0, Bsz * 4, stream);
        (void)hipMemsetAsync(flags, 0, 256 * 16 * 4, stream);

        conv_lstm_cat<PRE + ENCD, ARNN><<<4096, 256, 0, stream>>>(
            aWih, aWhh, abih, abhh, Wcat_a, bsum_a);
        conv_lstm_cat<ARNN + ENCD, DRNN><<<4096, 256, 0, stream>>>(
            dWih, dWhh, dbih, dbhh, Wcat_d, bsum_d);
        conv_mat<<<768, 256, 0, stream>>>(oW, Wo, NSYM * (DRNN + ENCD));
        conv_mat<<<4096, 256, 0, stream>>>(memory, mem16, Bsz * Lmem * ENCD);
        prenet_kernel<<<Tsteps * Bsz / 8, 256, 0, stream>>>(din, pW1, pb1, pW2, pb2, xpre);

        decoder_2bar<<<256, 512, 0, stream>>>(
            Wcat_a, bsum_a, Wcat_d, bsum_d, Wo, ob, xpre,
            attWp, attbp, mlen, mem16,
            ah0, ah1, dh0, dh1, ctx0, ctx1, mean0, mean1,
            logits, aligns, ps, flags);
    }
}